// Round 5
// baseline (126.293 us; speedup 1.0000x reference)
//
#include <hip/hip_runtime.h>
#include <hip/hip_bf16.h>

#define EE 256
#define HIDD 150
#define HP 160
#define NN 384
#define NB 2
#define JTILE 64
#define NJT 6
#define RPB 8
#define HTSTRIDE 168  // halfs per Ht row (336B): worst 2-way bank aliasing (free)

typedef float f32x4 __attribute__((ext_vector_type(4)));
typedef _Float16 half8 __attribute__((ext_vector_type(8)));
typedef _Float16 half4 __attribute__((ext_vector_type(4)));

__device__ __forceinline__ void gload16(const _Float16* g, _Float16* l) {
  __builtin_amdgcn_global_load_lds(
      (const __attribute__((address_space(1))) unsigned int*)g,
      (__attribute__((address_space(3))) unsigned int*)l, 16, 0, 0);
}

// ---- pack W1c (rows 512..767 of W1) and W2 (+b2 in k-row 150) into MFMA frag order, fp16 ----
// frag k-convention: index=lane&15, k=(lane>>4)*8+e (within each 32-K step)
__global__ void pack_weights(const float* __restrict__ W1, const float* __restrict__ W2,
                             const float* __restrict__ b2,
                             _Float16* __restrict__ w1p, _Float16* __restrict__ w2p) {
  int idx = blockIdx.x * blockDim.x + threadIdx.x;
  if (idx < 40960) {
    int e = idx & 7, lane = (idx >> 3) & 63, tile = idx >> 9;
    int t = tile % 10, k8 = tile / 10;
    int eg = k8 * 32 + ((lane >> 4) << 3) + e;
    int h = t * 16 + (lane & 15);
    w1p[idx] = (_Float16)((h < HIDD) ? W1[(512 + eg) * HIDD + h] : 0.f);
  }
  int idx2 = idx - 40960;
  if (idx2 >= 0 && idx2 < 25600) {
    int e = idx2 & 7, lane = (idx2 >> 3) & 63, tile = idx2 >> 9;
    int t = tile % 10, k5 = tile / 10;
    int kk = k5 * 32 + ((lane >> 4) << 3) + e;
    int h = t * 16 + (lane & 15);
    float v = 0.f;
    if (h < HIDD) {
      if (kk < HIDD) v = W2[kk * HIDD + h];
      else if (kk == HIDD) v = b2[h];   // b2 folded: h1[.][150] forced to 1.0 in main
    }
    w2p[idx2] = (_Float16)v;
  }
}

// ---- U[bn][h] = x@W1a + b1 ; V[bn][h] = x@W1b (both f32 row-major) ; Xh = fp16(X) ----
__global__ void compute_uv(const float* __restrict__ X, const float* __restrict__ W1,
                           const float* __restrict__ b1,
                           _Float16* __restrict__ Xh, float* __restrict__ U,
                           float* __restrict__ V) {
  int r0 = blockIdx.x * RPB;
  int tid = threadIdx.x;
  __shared__ float xs[RPB][EE];
  for (int q = tid; q < RPB * EE; q += 256) {
    float xv = X[r0 * EE + q];
    xs[q >> 8][q & 255] = xv;
    Xh[r0 * EE + q] = (_Float16)xv;
  }
  __syncthreads();
  int h = tid;
  if (h < HP) {
    float u[RPB] = {0,0,0,0,0,0,0,0}, v[RPB] = {0,0,0,0,0,0,0,0};
    if (h < HIDD) {
      for (int e = 0; e < EE; e++) {
        float wa = W1[e * HIDD + h];
        float wb = W1[(EE + e) * HIDD + h];
        #pragma unroll
        for (int r = 0; r < RPB; r++) {
          u[r] = fmaf(xs[r][e], wa, u[r]);
          v[r] = fmaf(xs[r][e], wb, v[r]);
        }
      }
      float bb = b1[h];
      #pragma unroll
      for (int r = 0; r < RPB; r++) u[r] += bb;
    }
    #pragma unroll
    for (int r = 0; r < RPB; r++) {
      U[(r0 + r) * HP + h] = u[r];
      V[(r0 + r) * HP + h] = v[r];
    }
  }
}

// ---- main: block = (b, i-pair, j-tile of 64); 2 waves, wave w owns i = i0+w, 64 j each ----
// Weights stream L2 -> LDS via async global_load_lds (double-buffered 10KB chunks);
// fragments come from ds_read_b128. GEMM1 computed transposed (C1^T = W1c^T x (xi.xj)).
__global__ __launch_bounds__(128, 1) void pair_main(
    const _Float16* __restrict__ Xh, const float* __restrict__ M,
    const float* __restrict__ W3, const float* __restrict__ b3,
    const float* __restrict__ U, const float* __restrict__ V,
    const _Float16* __restrict__ w1p, const _Float16* __restrict__ w2p,
    float* __restrict__ out) {
  int bx = blockIdx.x;
  int jt = bx % NJT;
  int ig = (bx / NJT) % (NN / 2);
  int b = bx / (NJT * (NN / 2));
  int i0 = ig * 2;

  int tid = threadIdx.x;
  int lane = tid & 63;
  int w = tid >> 6;
  int hcol = lane & 15;
  int rgrp = lane >> 4;
  int i = i0 + w;

  __shared__ __align__(16) _Float16 wbuf[2][5120];      // 10 t-tiles x 1KB per chunk
  __shared__ __align__(16) _Float16 Ht[2][64 * HTSTRIDE];
  __shared__ __align__(16) _Float16 xs[2][EE];
  __shared__ float Uf[2][HP];
  __shared__ float W3s[HP];
  __shared__ float ms[JTILE];

  // issue chunk-0 staging first; its latency hides under the prologue
  {
    const _Float16* src = w1p + w * 2560 + lane * 8;
    _Float16* dst = &wbuf[0][w * 2560];
    #pragma unroll
    for (int is = 0; is < 5; is++) gload16(src + is * 512, dst + is * 512);
  }

  for (int q = tid; q < 256; q += 128)
    reinterpret_cast<unsigned*>(&xs[0][0])[q] =
        reinterpret_cast<const unsigned*>(Xh + (size_t)(b * NN + i0) * EE)[q];
  for (int q = tid; q < 2 * HP; q += 128)
    (&Uf[0][0])[q] = U[(b * NN + i0) * HP + q];
  for (int q = tid; q < HP; q += 128) W3s[q] = (q < HIDD) ? W3[q] : 0.f;
  if (tid < JTILE) ms[tid] = M[b * NN + jt * JTILE + tid];
  __syncthreads();

  // xj row gathers (4 A-subtiles), k-slice 0 preloaded
  const _Float16* xrb = Xh + (size_t)(b * NN + jt * JTILE + hcol) * EE + rgrp * 8;
  half8 xjc[4], xjn[4];
  #pragma unroll
  for (int af = 0; af < 4; af++)
    xjc[af] = *reinterpret_cast<const half8*>(xrb + af * 16 * EE);

  // acc = C1^T[h,j], init U[i,h] + V[j,h]
  f32x4 acc[4][10];
  #pragma unroll
  for (int t = 0; t < 10; t++) {
    int h0 = t * 16 + rgrp * 4;
    float4 u4 = *reinterpret_cast<const float4*>(&Uf[w][h0]);
    #pragma unroll
    for (int af = 0; af < 4; af++) {
      int jr = b * NN + jt * JTILE + af * 16 + hcol;
      float4 v4 = *reinterpret_cast<const float4*>(V + jr * HP + h0);
      acc[af][t][0] = u4.x + v4.x; acc[af][t][1] = u4.y + v4.y;
      acc[af][t][2] = u4.z + v4.z; acc[af][t][3] = u4.w + v4.w;
    }
  }

  // ---- GEMM1: 8 K-chunks; stage next while computing current ----
  int buf = 0;
  #pragma unroll
  for (int k8 = 0; k8 < 8; k8++) {
    {
      const _Float16* src = (k8 < 7) ? (w1p + (k8 + 1) * 5120 + w * 2560 + lane * 8)
                                     : (w2p + w * 2560 + lane * 8);
      _Float16* dst = &wbuf[buf ^ 1][w * 2560];
      #pragma unroll
      for (int is = 0; is < 5; is++) gload16(src + is * 512, dst + is * 512);
    }
    __syncthreads();  // chunk k8 landed
    if (k8 < 7) {
      #pragma unroll
      for (int af = 0; af < 4; af++)
        xjn[af] = *reinterpret_cast<const half8*>(xrb + af * 16 * EE + (k8 + 1) * 32);
    }
    half8 xi_s = *reinterpret_cast<const half8*>(&xs[w][k8 * 32 + rgrp * 8]);
    half8 a0 = xi_s * xjc[0], a1 = xi_s * xjc[1];
    half8 a2 = xi_s * xjc[2], a3 = xi_s * xjc[3];
    #pragma unroll
    for (int t = 0; t < 10; t++) {
      half8 bf = *reinterpret_cast<const half8*>(&wbuf[buf][t * 512 + lane * 8]);
      acc[0][t] = __builtin_amdgcn_mfma_f32_16x16x32_f16(bf, a0, acc[0][t], 0, 0, 0);
      acc[1][t] = __builtin_amdgcn_mfma_f32_16x16x32_f16(bf, a1, acc[1][t], 0, 0, 0);
      acc[2][t] = __builtin_amdgcn_mfma_f32_16x16x32_f16(bf, a2, acc[2][t], 0, 0, 0);
      acc[3][t] = __builtin_amdgcn_mfma_f32_16x16x32_f16(bf, a3, acc[3][t], 0, 0, 0);
    }
    __syncthreads();  // all lanes done with buf before restage
    if (k8 < 7) {
      #pragma unroll
      for (int af = 0; af < 4; af++) xjc[af] = xjn[af];
    }
    buf ^= 1;
  }

  // relu -> fp16 -> wave-private Ht[j][h], vectorized ds_write_b64 (4 h per write)
  _Float16* hw = &Ht[w][0];
  #pragma unroll
  for (int af = 0; af < 4; af++) {
    int row = af * 16 + hcol;
    #pragma unroll
    for (int t = 0; t < 10; t++) {
      half4 hv;
      hv[0] = (_Float16)fmaxf(acc[af][t][0], 0.f);
      hv[1] = (_Float16)fmaxf(acc[af][t][1], 0.f);
      hv[2] = (_Float16)fmaxf(acc[af][t][2], 0.f);
      hv[3] = (_Float16)fmaxf(acc[af][t][3], 0.f);
      *reinterpret_cast<half4*>(hw + row * HTSTRIDE + t * 16 + rgrp * 4) = hv;
    }
  }
  {  // k-row 150 = 1.0 (b2 via weights), 151..159 = 0; one j-row per lane
    _Float16* hr = hw + lane * HTSTRIDE;
    hr[150] = (_Float16)1.0f;
    hr[151] = (_Float16)0.0f;
    half4 z = {(_Float16)0.f, (_Float16)0.f, (_Float16)0.f, (_Float16)0.f};
    *reinterpret_cast<half4*>(hr + 152) = z;
    *reinterpret_cast<half4*>(hr + 156) = z;
  }

  // ---- GEMM2: D2[j,h2], 5 K-chunks ----
  #pragma unroll
  for (int af = 0; af < 4; af++)
    #pragma unroll
    for (int t = 0; t < 10; t++) {
      acc[af][t][0] = 0.f; acc[af][t][1] = 0.f;
      acc[af][t][2] = 0.f; acc[af][t][3] = 0.f;
    }
  #pragma unroll
  for (int k5 = 0; k5 < 5; k5++) {
    if (k5 < 4) {
      const _Float16* src = w2p + (k5 + 1) * 5120 + w * 2560 + lane * 8;
      _Float16* dst = &wbuf[buf ^ 1][w * 2560];
      #pragma unroll
      for (int is = 0; is < 5; is++) gload16(src + is * 512, dst + is * 512);
    }
    __syncthreads();
    half8 a[4];
    #pragma unroll
    for (int af = 0; af < 4; af++)
      a[af] = *reinterpret_cast<const half8*>(
          hw + (af * 16 + hcol) * HTSTRIDE + k5 * 32 + rgrp * 8);
    #pragma unroll
    for (int t = 0; t < 10; t++) {
      half8 bf = *reinterpret_cast<const half8*>(&wbuf[buf][t * 512 + lane * 8]);
      acc[0][t] = __builtin_amdgcn_mfma_f32_16x16x32_f16(a[0], bf, acc[0][t], 0, 0, 0);
      acc[1][t] = __builtin_amdgcn_mfma_f32_16x16x32_f16(a[1], bf, acc[1][t], 0, 0, 0);
      acc[2][t] = __builtin_amdgcn_mfma_f32_16x16x32_f16(a[2], bf, acc[2][t], 0, 0, 0);
      acc[3][t] = __builtin_amdgcn_mfma_f32_16x16x32_f16(a[3], bf, acc[3][t], 0, 0, 0);
    }
    __syncthreads();
    buf ^= 1;
  }

  // layer 3: s[j] = sum_h relu(h2)[j,h] * W3[h], 16-lane shuffle reduce
  float mi = M[b * NN + i];
  float bb3 = b3[0];
  #pragma unroll
  for (int af = 0; af < 4; af++) {
    float pr0 = 0.f, pr1 = 0.f, pr2 = 0.f, pr3 = 0.f;
    #pragma unroll
    for (int t = 0; t < 10; t++) {
      float w3 = W3s[t * 16 + hcol];
      pr0 = fmaf(fmaxf(acc[af][t][0], 0.f), w3, pr0);
      pr1 = fmaf(fmaxf(acc[af][t][1], 0.f), w3, pr1);
      pr2 = fmaf(fmaxf(acc[af][t][2], 0.f), w3, pr2);
      pr3 = fmaf(fmaxf(acc[af][t][3], 0.f), w3, pr3);
    }
    #pragma unroll
    for (int mk = 1; mk <= 8; mk <<= 1) {
      pr0 += __shfl_xor(pr0, mk);
      pr1 += __shfl_xor(pr1, mk);
      pr2 += __shfl_xor(pr2, mk);
      pr3 += __shfl_xor(pr3, mk);
    }
    if (hcol == 0) {
      int jl0 = af * 16 + rgrp * 4;
      float4 o;
      o.x = (mi + ms[jl0 + 0] + pr0 + bb3) * (1.f / 3.f);
      o.y = (mi + ms[jl0 + 1] + pr1 + bb3) * (1.f / 3.f);
      o.z = (mi + ms[jl0 + 2] + pr2 + bb3) * (1.f / 3.f);
      o.w = (mi + ms[jl0 + 3] + pr3 + bb3) * (1.f / 3.f);
      *reinterpret_cast<float4*>(out + (b * NN + i) * NN + jt * JTILE + jl0) = o;
    }
  }
}

extern "C" void kernel_launch(void* const* d_in, const int* in_sizes, int n_in,
                              void* d_out, int out_size, void* d_ws, size_t ws_size,
                              hipStream_t stream) {
  const float* X  = (const float*)d_in[0];
  const float* M  = (const float*)d_in[1];
  const float* W1 = (const float*)d_in[2];
  const float* b1 = (const float*)d_in[3];
  const float* W2 = (const float*)d_in[4];
  const float* b2 = (const float*)d_in[5];
  const float* W3 = (const float*)d_in[6];
  const float* b3 = (const float*)d_in[7];
  float* out = (float*)d_out;

  float* U  = (float*)d_ws;                        // 768*160 f32
  float* V  = U + NB * NN * HP;                    // 768*160 f32
  _Float16* Xh  = (_Float16*)(V + NB * NN * HP);   // 768*256 f16
  _Float16* w1p = Xh + NB * NN * EE;               // 40960 f16
  _Float16* w2p = w1p + 40960;                     // 25600 f16

  hipLaunchKernelGGL(pack_weights, dim3(260), dim3(256), 0, stream, W1, W2, b2, w1p, w2p);
  hipLaunchKernelGGL(compute_uv, dim3(NB * NN / RPB), dim3(256), 0, stream, X, W1, b1, Xh, U, V);
  hipLaunchKernelGGL(pair_main, dim3(NB * (NN / 2) * NJT), dim3(128), 0, stream,
                     Xh, M, W3, b3, U, V, w1p, w2p, out);
}

// Round 6
// 94.581 us; speedup vs baseline: 1.3353x; 1.3353x over previous
//
#include <hip/hip_runtime.h>
#include <hip/hip_bf16.h>

#define EE 256
#define HIDD 150
#define HP 160
#define NN 384
#define NB 2
#define NJT 6
#define RPB 4
#define HTS 168  // Ht row stride in halfs (336B = 21*16: rows stay 16B-aligned)

typedef float f32x4 __attribute__((ext_vector_type(4)));
typedef _Float16 half8 __attribute__((ext_vector_type(8)));
typedef _Float16 half4 __attribute__((ext_vector_type(4)));

__device__ __forceinline__ void gload16(const _Float16* g, _Float16* l) {
  __builtin_amdgcn_global_load_lds(
      (const __attribute__((address_space(1))) unsigned int*)g,
      (__attribute__((address_space(3))) unsigned int*)l, 16, 0, 0);
}

// ---- pack W1c (rows 512..767 of W1) and W2 (+b2 in k-row 150) into MFMA frag order, fp16 ----
// frag k-convention: index=lane&15, k=(lane>>4)*8+e (within each 32-K step)
__global__ void pack_weights(const float* __restrict__ W1, const float* __restrict__ W2,
                             const float* __restrict__ b2,
                             _Float16* __restrict__ w1p, _Float16* __restrict__ w2p) {
  int idx = blockIdx.x * blockDim.x + threadIdx.x;
  if (idx < 40960) {
    int e = idx & 7, lane = (idx >> 3) & 63, tile = idx >> 9;
    int t = tile % 10, k8 = tile / 10;
    int eg = k8 * 32 + ((lane >> 4) << 3) + e;
    int h = t * 16 + (lane & 15);
    w1p[idx] = (_Float16)((h < HIDD) ? W1[(512 + eg) * HIDD + h] : 0.f);
  }
  int idx2 = idx - 40960;
  if (idx2 >= 0 && idx2 < 25600) {
    int e = idx2 & 7, lane = (idx2 >> 3) & 63, tile = idx2 >> 9;
    int t = tile % 10, k5 = tile / 10;
    int kk = k5 * 32 + ((lane >> 4) << 3) + e;
    int h = t * 16 + (lane & 15);
    float v = 0.f;
    if (h < HIDD) {
      if (kk < HIDD) v = W2[kk * HIDD + h];
      else if (kk == HIDD) v = b2[h];   // b2 folded: h1[.][150] forced to 1.0 in main
    }
    w2p[idx2] = (_Float16)v;
  }
}

// ---- U[bn][h] = x@W1a + b1 ; V[bn][h] = x@W1b (both f32 row-major) ; Xh = fp16(X) ----
__global__ void compute_uv(const float* __restrict__ X, const float* __restrict__ W1,
                           const float* __restrict__ b1,
                           _Float16* __restrict__ Xh, float* __restrict__ U,
                           float* __restrict__ V) {
  int r0 = blockIdx.x * RPB;
  int tid = threadIdx.x;
  __shared__ float xs[RPB][EE];
  for (int q = tid; q < RPB * EE; q += 256) {
    float xv = X[r0 * EE + q];
    xs[q >> 8][q & 255] = xv;
    Xh[r0 * EE + q] = (_Float16)xv;
  }
  __syncthreads();
  int h = tid;
  if (h < HP) {
    float u[RPB] = {0, 0, 0, 0}, v[RPB] = {0, 0, 0, 0};
    if (h < HIDD) {
      for (int e = 0; e < EE; e++) {
        float wa = W1[e * HIDD + h];
        float wb = W1[(EE + e) * HIDD + h];
        #pragma unroll
        for (int r = 0; r < RPB; r++) {
          u[r] = fmaf(xs[r][e], wa, u[r]);
          v[r] = fmaf(xs[r][e], wb, v[r]);
        }
      }
      float bb = b1[h];
      #pragma unroll
      for (int r = 0; r < RPB; r++) u[r] += bb;
    }
    #pragma unroll
    for (int r = 0; r < RPB; r++) {
      U[(r0 + r) * HP + h] = u[r];
      V[(r0 + r) * HP + h] = v[r];
    }
  }
}

// ---- main: block = (b, i-pair, j-tile 64); 4 waves; wave w: i = i0+(w>>1), j-half (w&1) ----
// One sync per weight chunk: sync -> stage(next, buf^1) -> compute(buf); the fresh stage
// flies under this chunk's MFMAs and is drained by the NEXT iteration's sync.
__global__ __launch_bounds__(256, 2) void pair_main(
    const _Float16* __restrict__ Xh, const float* __restrict__ M,
    const float* __restrict__ W3, const float* __restrict__ b3,
    const float* __restrict__ U, const float* __restrict__ V,
    const _Float16* __restrict__ w1p, const _Float16* __restrict__ w2p,
    float* __restrict__ out) {
  int bx = blockIdx.x;
  int jt = bx % NJT;
  int ig = (bx / NJT) % (NN / 2);
  int b = bx / (NJT * (NN / 2));
  int i0 = ig * 2;

  int tid = threadIdx.x;
  int lane = tid & 63;
  int w = tid >> 6;
  int hcol = lane & 15;
  int rgrp = lane >> 4;
  int il = w >> 1;
  int jh = w & 1;
  int i = i0 + il;

  __shared__ __align__(16) _Float16 wbuf[2][5120];     // 10 t-tiles x 1KB per chunk
  __shared__ __align__(16) _Float16 Ht[4][32 * HTS];   // per-wave 32 j-rows
  __shared__ __align__(16) _Float16 xs[2][EE];
  __shared__ float Uf[2][HP];
  __shared__ float W3s[HP];
  __shared__ float ms[64];

  // chunk staging: 5120 halfs; 4 waves x 2 slots + waves 0,1 take the tail
  auto stage_chunk = [&](int c, int buf) {
    const _Float16* wsrc = (c < 8) ? (w1p + c * 5120) : (w2p + (c - 8) * 5120);
    _Float16* wdst = &wbuf[buf][0];
    gload16(wsrc + w * 512 + lane * 8, wdst + w * 512);
    gload16(wsrc + (4 + w) * 512 + lane * 8, wdst + (4 + w) * 512);
    if (w < 2) gload16(wsrc + (8 + w) * 512 + lane * 8, wdst + (8 + w) * 512);
  };

  stage_chunk(0, 0);  // in flight during prologue

  reinterpret_cast<unsigned*>(&xs[0][0])[tid] =
      reinterpret_cast<const unsigned*>(Xh + (size_t)(b * NN + i0) * EE)[tid];
  for (int q = tid; q < 2 * HP; q += 256)
    (&Uf[0][0])[q] = U[(b * NN + i0) * HP + q];
  if (tid < HP) W3s[tid] = (tid < HIDD) ? W3[tid] : 0.f;
  if (tid < 64) ms[tid] = M[b * NN + jt * 64 + tid];
  __syncthreads();  // LDS staging visible; chunk 0 drained

  // wave's 2 j sub-tiles: rows jt*64 + jh*32 + jf*16 + hcol
  const _Float16* xr0 = Xh + (size_t)(b * NN + jt * 64 + jh * 32 + hcol) * EE;
  const _Float16* xr1 = xr0 + 16 * EE;

  // acc = C1^T[h, j]; init U[i,h] + V[j,h]
  f32x4 acc[2][10];
  #pragma unroll
  for (int t = 0; t < 10; t++) {
    int h0 = t * 16 + rgrp * 4;
    float4 u4 = *reinterpret_cast<const float4*>(&Uf[il][h0]);
    #pragma unroll
    for (int jf = 0; jf < 2; jf++) {
      int jr = b * NN + jt * 64 + jh * 32 + jf * 16 + hcol;
      float4 v4 = *reinterpret_cast<const float4*>(V + jr * HP + h0);
      acc[jf][t][0] = u4.x + v4.x; acc[jf][t][1] = u4.y + v4.y;
      acc[jf][t][2] = u4.z + v4.z; acc[jf][t][3] = u4.w + v4.w;
    }
  }

  // ---- GEMM1: C1^T[h,j] += W1c^T (xi.xj), 8 K-chunks ----
  half8 xjc0 = *reinterpret_cast<const half8*>(xr0 + rgrp * 8);
  half8 xjc1 = *reinterpret_cast<const half8*>(xr1 + rgrp * 8);
  int buf = 0;
  #pragma unroll
  for (int k8 = 0; k8 < 8; k8++) {
    __syncthreads();                 // prev chunk read-done + this chunk landed
    stage_chunk(k8 + 1, buf ^ 1);    // k8=7 stages chunk 8 (w2p k5=0)
    half8 xi_s = *reinterpret_cast<const half8*>(&xs[il][k8 * 32 + rgrp * 8]);
    half8 a0 = xi_s * xjc0;
    half8 a1 = xi_s * xjc1;
    if (k8 < 7) {
      xjc0 = *reinterpret_cast<const half8*>(xr0 + (k8 + 1) * 32 + rgrp * 8);
      xjc1 = *reinterpret_cast<const half8*>(xr1 + (k8 + 1) * 32 + rgrp * 8);
    }
    #pragma unroll
    for (int t = 0; t < 10; t++) {
      half8 bf = *reinterpret_cast<const half8*>(&wbuf[buf][t * 512 + lane * 8]);
      acc[0][t] = __builtin_amdgcn_mfma_f32_16x16x32_f16(bf, a0, acc[0][t], 0, 0, 0);
      acc[1][t] = __builtin_amdgcn_mfma_f32_16x16x32_f16(bf, a1, acc[1][t], 0, 0, 0);
    }
    buf ^= 1;
  }

  // relu -> fp16 -> wave-private Ht[j][h]; byte-XOR swizzle on bits 4..5 (alignment-safe)
  char* hw = reinterpret_cast<char*>(&Ht[w][0]);
  #pragma unroll
  for (int jf = 0; jf < 2; jf++) {
    int row = jf * 16 + hcol;
    int sw = (row & 3) << 4;
    #pragma unroll
    for (int t = 0; t < 10; t++) {
      half4 hv;
      hv[0] = (_Float16)fmaxf(acc[jf][t][0], 0.f);
      hv[1] = (_Float16)fmaxf(acc[jf][t][1], 0.f);
      hv[2] = (_Float16)fmaxf(acc[jf][t][2], 0.f);
      hv[3] = (_Float16)fmaxf(acc[jf][t][3], 0.f);
      *reinterpret_cast<half4*>(hw + ((row * 336 + t * 32 + rgrp * 8) ^ sw)) = hv;
    }
  }
  if (lane < 32) {  // pad h=150..159: 150 -> 1.0 (b2 via W2 k-row), rest 0
    int row = lane;
    int sw = (row & 3) << 4;
    half4 z = {(_Float16)0.f, (_Float16)0.f, (_Float16)0.f, (_Float16)0.f};
    *reinterpret_cast<_Float16*>(hw + ((row * 336 + 300) ^ sw)) = (_Float16)1.0f;
    *reinterpret_cast<_Float16*>(hw + ((row * 336 + 302) ^ sw)) = (_Float16)0.0f;
    *reinterpret_cast<half4*>(hw + ((row * 336 + 304) ^ sw)) = z;
    *reinterpret_cast<half4*>(hw + ((row * 336 + 312) ^ sw)) = z;
  }

  // ---- GEMM2: D2[j,h2], 5 K-chunks (chunks 8..12) ----
  #pragma unroll
  for (int jf = 0; jf < 2; jf++)
    #pragma unroll
    for (int t = 0; t < 10; t++) {
      acc[jf][t][0] = 0.f; acc[jf][t][1] = 0.f;
      acc[jf][t][2] = 0.f; acc[jf][t][3] = 0.f;
    }
  #pragma unroll
  for (int k5 = 0; k5 < 5; k5++) {
    __syncthreads();
    if (k5 < 4) stage_chunk(9 + k5, buf ^ 1);
    half8 a0 = *reinterpret_cast<const half8*>(
        hw + ((hcol * 336 + k5 * 64 + rgrp * 16) ^ ((hcol & 3) << 4)));
    half8 a1 = *reinterpret_cast<const half8*>(
        hw + (((16 + hcol) * 336 + k5 * 64 + rgrp * 16) ^ ((hcol & 3) << 4)));
    #pragma unroll
    for (int t = 0; t < 10; t++) {
      half8 bf = *reinterpret_cast<const half8*>(&wbuf[buf][t * 512 + lane * 8]);
      acc[0][t] = __builtin_amdgcn_mfma_f32_16x16x32_f16(a0, bf, acc[0][t], 0, 0, 0);
      acc[1][t] = __builtin_amdgcn_mfma_f32_16x16x32_f16(a1, bf, acc[1][t], 0, 0, 0);
    }
    buf ^= 1;
  }

  // layer 3: s[j] = sum_h2 relu(D2[j,h2]) * W3[h2]; reduce over hcol lanes
  float bb3 = b3[0];
  float mi = M[b * NN + i];
  #pragma unroll
  for (int jf = 0; jf < 2; jf++) {
    float pr0 = 0.f, pr1 = 0.f, pr2 = 0.f, pr3 = 0.f;
    #pragma unroll
    for (int t = 0; t < 10; t++) {
      float w3 = W3s[t * 16 + hcol];
      pr0 = fmaf(fmaxf(acc[jf][t][0], 0.f), w3, pr0);
      pr1 = fmaf(fmaxf(acc[jf][t][1], 0.f), w3, pr1);
      pr2 = fmaf(fmaxf(acc[jf][t][2], 0.f), w3, pr2);
      pr3 = fmaf(fmaxf(acc[jf][t][3], 0.f), w3, pr3);
    }
    #pragma unroll
    for (int mk = 1; mk <= 8; mk <<= 1) {
      pr0 += __shfl_xor(pr0, mk);
      pr1 += __shfl_xor(pr1, mk);
      pr2 += __shfl_xor(pr2, mk);
      pr3 += __shfl_xor(pr3, mk);
    }
    if (hcol == 0) {
      int jl = jh * 32 + jf * 16 + rgrp * 4;
      float4 o;
      o.x = (mi + ms[jl + 0] + pr0 + bb3) * (1.f / 3.f);
      o.y = (mi + ms[jl + 1] + pr1 + bb3) * (1.f / 3.f);
      o.z = (mi + ms[jl + 2] + pr2 + bb3) * (1.f / 3.f);
      o.w = (mi + ms[jl + 3] + pr3 + bb3) * (1.f / 3.f);
      *reinterpret_cast<float4*>(out + (size_t)(b * NN + i) * NN + jt * 64 + jl) = o;
    }
  }
}

extern "C" void kernel_launch(void* const* d_in, const int* in_sizes, int n_in,
                              void* d_out, int out_size, void* d_ws, size_t ws_size,
                              hipStream_t stream) {
  const float* X  = (const float*)d_in[0];
  const float* M  = (const float*)d_in[1];
  const float* W1 = (const float*)d_in[2];
  const float* b1 = (const float*)d_in[3];
  const float* W2 = (const float*)d_in[4];
  const float* b2 = (const float*)d_in[5];
  const float* W3 = (const float*)d_in[6];
  const float* b3 = (const float*)d_in[7];
  float* out = (float*)d_out;

  float* U  = (float*)d_ws;                        // 768*160 f32
  float* V  = U + NB * NN * HP;                    // 768*160 f32
  _Float16* Xh  = (_Float16*)(V + NB * NN * HP);   // 768*256 f16
  _Float16* w1p = Xh + NB * NN * EE;               // 40960 f16
  _Float16* w2p = w1p + 40960;                     // 25600 f16

  hipLaunchKernelGGL(pack_weights, dim3(260), dim3(256), 0, stream, W1, W2, b2, w1p, w2p);
  hipLaunchKernelGGL(compute_uv, dim3(NB * NN / RPB), dim3(256), 0, stream, X, W1, b1, Xh, U, V);
  hipLaunchKernelGGL(pair_main, dim3(NB * (NN / 2) * NJT), dim3(256), 0, stream,
                     Xh, M, W3, b3, U, V, w1p, w2p, out);
}